// Round 6
// baseline (251.076 us; speedup 1.0000x reference)
//
#include <hip/hip_runtime.h>
#include <hip/hip_bf16.h>

// Problem constants (from reference)
#define BATCH_N   16384
#define FEAT      128      // MOVIE_FEAT == USER_FEAT
#define NNBR      50
#define NUM_MOVIES_N 100000

typedef short  short8  __attribute__((ext_vector_type(8)));
typedef float  floatx4 __attribute__((ext_vector_type(4)));
typedef unsigned int u32;

__device__ __forceinline__ __hip_bfloat16 f2bf(float x) { return __float2bfloat16(x); }
__device__ __forceinline__ float bfb2f(short s) {
  union { u32 u; float f; } c; c.u = ((u32)(unsigned short)s) << 16; return c.f;
}

__device__ __forceinline__ floatx4 mfma16(short8 a, short8 b, floatx4 c) {
  return __builtin_amdgcn_mfma_f32_16x16x32_bf16(a, b, c, 0, 0, 0);
}

// ---------------------------------------------------------------------------
// conv_table: fp32 movie_table -> bf16 copy (25 MB, L2/L3-resident for gathers)
// ---------------------------------------------------------------------------
__global__ __launch_bounds__(256) void conv_table(
    const float* __restrict__ t, __hip_bfloat16* __restrict__ tb) {
  size_t i = ((size_t)blockIdx.x * 256 + threadIdx.x) * 8;
  float4 v0 = *(const float4*)(t + i);
  float4 v1 = *(const float4*)(t + i + 4);
  __hip_bfloat16 o[8];
  o[0] = f2bf(v0.x); o[1] = f2bf(v0.y); o[2] = f2bf(v0.z); o[3] = f2bf(v0.w);
  o[4] = f2bf(v1.x); o[5] = f2bf(v1.y); o[6] = f2bf(v1.z); o[7] = f2bf(v1.w);
  *(short8*)(tb + i) = *(short8*)o;
}

// ---------------------------------------------------------------------------
// prep: bf16 transposed weights Wt[n][k] + fused bias bu+bm.
// WcatT=[Wu;Wm]^T [256n][256k]; W1T [256][256]; W2T [128n][256k]; WmT [256n][128k]
// ---------------------------------------------------------------------------
__global__ __launch_bounds__(256) void prep_kernel(
    const float* __restrict__ Wu, const float* __restrict__ Wm,
    const float* __restrict__ W1, const float* __restrict__ W2,
    const float* __restrict__ bu, const float* __restrict__ bm,
    __hip_bfloat16* __restrict__ WcatT, __hip_bfloat16* __restrict__ WmT,
    __hip_bfloat16* __restrict__ W1T,  __hip_bfloat16* __restrict__ W2T,
    float* __restrict__ bc) {
  int idx = blockIdx.x * 256 + threadIdx.x;   // 0..65535
  int n = idx & 255, k = idx >> 8;
  float v = (k < 128) ? Wu[k * 256 + n] : Wm[(k - 128) * 256 + n];
  WcatT[n * 256 + k] = f2bf(v);
  W1T[n * 256 + k]   = f2bf(W1[k * 256 + n]);
  if (k < 128) WmT[n * 128 + k] = f2bf(Wm[k * 256 + n]);
  if (idx < 32768) {
    int k2 = idx >> 7, n2 = idx & 127;
    W2T[n2 * 256 + k2] = f2bf(W2[k2 * 128 + n2]);
  }
  if (idx < 256) bc[idx] = bu[idx] + bm[idx];
}

// ---------------------------------------------------------------------------
// gather_user: one WAVE per batch row. Lane slice = 16 B; quad q handles
// nbr 4*it+q -> 13 wave-loads of 1 KB. Cross-quad shfl_xor reduce.
// ---------------------------------------------------------------------------
__global__ __launch_bounds__(256) void gather_user(
    const float* __restrict__ users, const int* __restrict__ nbr_ids,
    const __hip_bfloat16* __restrict__ tb, __hip_bfloat16* __restrict__ A_user) {
  int row  = (blockIdx.x << 2) + (threadIdx.x >> 6);
  int lane = threadIdx.x & 63;
  int quad = lane >> 4, sl = lane & 15;
  const int* nb = nbr_ids + row * NNBR;
  float acc[8] = {0.f, 0.f, 0.f, 0.f, 0.f, 0.f, 0.f, 0.f};
  #pragma unroll
  for (int it = 0; it < 13; ++it) {
    int j = it * 4 + quad;
    if (j < NNBR) {
      int id = nb[j];
      short8 v = *(const short8*)(tb + (size_t)id * FEAT + sl * 8);
      #pragma unroll
      for (int e = 0; e < 8; ++e) acc[e] += bfb2f(v[e]);
    }
  }
  __hip_bfloat16 o[8];
  #pragma unroll
  for (int e = 0; e < 8; ++e) {
    float v = acc[e];
    v += __shfl_xor(v, 16, 64);
    v += __shfl_xor(v, 32, 64);
    o[e] = f2bf(v * (1.f / NNBR));
  }
  if (quad == 0)
    *(short8*)(A_user + (size_t)row * 256 + 128 + sl * 8) = *(short8*)o;
  float2 uv = ((const float2*)(users + (size_t)row * FEAT))[lane];
  __hip_bfloat162 t0; t0.x = f2bf(uv.x); t0.y = f2bf(uv.y);
  ((__hip_bfloat162*)(A_user + (size_t)row * 256))[lane] = t0;
}

// ---------------------------------------------------------------------------
// gemm_bv: barrier-free GEMM, weights in VGPRs, A-frags direct from global.
//   C[M][NTOT] = act(A[M][K0] @ Wt^T + bias)
// Block = 256 thr = 4 waves; wave w owns cols [blockIdx.y*128 + w*32, +32).
// Per wave: B frags (2 j-tiles x KK kc) persist in VGPRs (loaded once, L2-hot).
// M-loop: IT iters x 16 rows. A-frags loaded as short8 straight from global:
// lane l reads row m0+(l&15), bytes [kc*64 + quad*16 .. +16) -> the 4 quads
// consume each row's full 64-B line (16 lines/instr, all fully used).
// Register double-buffer: next iter's 8 A-loads issue before this iter's
// MFMAs -> ~310 cy/SIMD of MFMA hides the L2 latency. No LDS, no barriers.
// 4 independent acc chains (2 j x 2 kc-parity) to break MFMA dependency.
// GATHER variant (layer-0 pos/neg): A row = tb[ids[m]] (id-indexed).
// ---------------------------------------------------------------------------
template <int K0, bool GATHER, bool RELU, bool OUTF32, int NTOT, int IT>
__global__ __launch_bounds__(256) void gemm_bv(
    const __hip_bfloat16* __restrict__ Asrc,
    const int* __restrict__ pos_ids, const int* __restrict__ neg_ids,
    const __hip_bfloat16* __restrict__ Wt, const float* __restrict__ bias,
    float* __restrict__ Cf, __hip_bfloat16* __restrict__ Cb) {
  constexpr int KK = K0 / 32;
  const int lane = threadIdx.x & 63, wid = threadIdx.x >> 6;
  const int quad = lane >> 4, lrow = lane & 15;
  const int c0 = blockIdx.y * 128 + wid * 32;
  const long mbase = (long)blockIdx.x * (16 * IT);

  // persistent B fragments for this wave's 32 columns (64 VGPRs @ K0=256)
  short8 bfr[2][KK];
  #pragma unroll
  for (int j = 0; j < 2; ++j)
    #pragma unroll
    for (int kc = 0; kc < KK; ++kc)
      bfr[j][kc] = *(const short8*)(Wt + (size_t)(c0 + j * 16 + lrow) * K0 +
                                    kc * 32 + quad * 8);
  const float bv0 = bias[c0 + lrow];
  const float bv1 = bias[c0 + 16 + lrow];

  short8 abuf[2][KK];
  auto loadA = [&](int it, short8* dst) {
    long m = mbase + it * 16 + lrow;
    const __hip_bfloat16* rp;
    if (GATHER) {
      int id = (m < BATCH_N) ? pos_ids[m] : neg_ids[m - BATCH_N];
      rp = Asrc + (size_t)id * K0;
    } else {
      rp = Asrc + (size_t)m * K0;
    }
    #pragma unroll
    for (int kc = 0; kc < KK; ++kc)
      dst[kc] = *(const short8*)(rp + kc * 32 + quad * 8);
  };

  loadA(0, abuf[0]);
  #pragma unroll
  for (int it = 0; it < IT; ++it) {
    if (it + 1 < IT) loadA(it + 1, abuf[(it + 1) & 1]);
    const short8* af = abuf[it & 1];
    floatx4 p0a = {}, p0b = {}, p1a = {}, p1b = {};
    #pragma unroll
    for (int kc = 0; kc < KK; kc += 2) {
      p0a = mfma16(af[kc],     bfr[0][kc],     p0a);
      p1a = mfma16(af[kc],     bfr[1][kc],     p1a);
      p0b = mfma16(af[kc + 1], bfr[0][kc + 1], p0b);
      p1b = mfma16(af[kc + 1], bfr[1][kc + 1], p1b);
    }
    floatx4 a0 = p0a + p0b, a1 = p1a + p1b;
    long m0 = mbase + it * 16;
    #pragma unroll
    for (int r = 0; r < 4; ++r) {
      long row = m0 + quad * 4 + r;
      float v0 = a0[r] + bv0, v1 = a1[r] + bv1;
      if (RELU) { v0 = fmaxf(v0, 0.f); v1 = fmaxf(v1, 0.f); }
      if (OUTF32) {
        Cf[row * NTOT + c0 + lrow]      = v0;
        Cf[row * NTOT + c0 + 16 + lrow] = v1;
      } else {
        Cb[row * NTOT + c0 + lrow]      = f2bf(v0);
        Cb[row * NTOT + c0 + 16 + lrow] = f2bf(v1);
      }
    }
  }
}

// ---------------------------------------------------------------------------
extern "C" void kernel_launch(void* const* d_in, const int* in_sizes, int n_in,
                              void* d_out, int out_size, void* d_ws, size_t ws_size,
                              hipStream_t stream) {
  const float* users   = (const float*)d_in[0];
  // d_in[1] pos_movies, d_in[2] neg_movies, d_in[3] user_ids: unused by ref
  const int*   pos_ids = (const int*)d_in[4];
  const int*   neg_ids = (const int*)d_in[5];
  const int*   nbr_ids = (const int*)d_in[6];
  const float* table   = (const float*)d_in[7];
  const float* Wu = (const float*)d_in[8];
  const float* bu = (const float*)d_in[9];
  const float* Wm = (const float*)d_in[10];
  const float* bm = (const float*)d_in[11];
  const float* W1 = (const float*)d_in[12];
  const float* b1 = (const float*)d_in[13];
  const float* W2 = (const float*)d_in[14];
  const float* b2 = (const float*)d_in[15];
  float* out = (float*)d_out;

  // workspace carve (all 256B aligned). Total ~83 MB.
  char* p = (char*)d_ws;
  auto carve = [&](size_t bytes) { char* r = p; p += (bytes + 255) & ~(size_t)255; return r; };
  __hip_bfloat16* tb     = (__hip_bfloat16*)carve((size_t)NUM_MOVIES_N * FEAT * 2);
  __hip_bfloat16* WcatT  = (__hip_bfloat16*)carve(256 * 256 * 2);
  __hip_bfloat16* WmT    = (__hip_bfloat16*)carve(256 * 128 * 2);
  __hip_bfloat16* W1T    = (__hip_bfloat16*)carve(256 * 256 * 2);
  __hip_bfloat16* W2T    = (__hip_bfloat16*)carve(128 * 256 * 2);
  float*          bc     = (float*)carve(256 * 4);
  __hip_bfloat16* A_user = (__hip_bfloat16*)carve((size_t)BATCH_N * 256 * 2);
  __hip_bfloat16* E      = (__hip_bfloat16*)carve((size_t)3 * BATCH_N * 256 * 2);
  __hip_bfloat16* H      = (__hip_bfloat16*)carve((size_t)3 * BATCH_N * 256 * 2);

  conv_table<<<NUM_MOVIES_N * FEAT / (256 * 8), 256, 0, stream>>>(table, tb);
  prep_kernel<<<256, 256, 0, stream>>>(Wu, Wm, W1, W2, bu, bm,
                                       WcatT, WmT, W1T, W2T, bc);
  gather_user<<<BATCH_N / 4, 256, 0, stream>>>(users, nbr_ids, tb, A_user);

  // E rows: [0,B) user | [B,2B) pos | [2B,3B) neg
  // L0-user: E[0:B] = A_user @ WcatT^T + bc          (M=16384, K=256, N=256)
  gemm_bv<256, false, false, false, 256, 4>
      <<<dim3(BATCH_N / 64, 2), 256, 0, stream>>>(
          A_user, nullptr, nullptr, WcatT, bc, nullptr, E);
  // L0-pn: E[B:3B] = tb[ids] @ WmT^T + bm            (M=32768, K=128, N=256)
  gemm_bv<128, true, false, false, 256, 4>
      <<<dim3(2 * BATCH_N / 64, 2), 256, 0, stream>>>(
          tb, pos_ids, neg_ids, WmT, bm, nullptr, E + (size_t)BATCH_N * 256);
  // L1: H = relu(E @ W1T^T + b1)                     (M=49152, K=256, N=256)
  gemm_bv<256, false, true, false, 256, 4>
      <<<dim3(3 * BATCH_N / 64, 2), 256, 0, stream>>>(
          E, nullptr, nullptr, W1T, b1, nullptr, H);
  // L2: out = relu(H @ W2T^T + b2)                   (M=49152, K=256, N=128)
  gemm_bv<256, false, true, true, 128, 4>
      <<<dim3(3 * BATCH_N / 64, 1), 256, 0, stream>>>(
          H, nullptr, nullptr, W2T, b2, out, nullptr);
}

// Round 7
// 242.896 us; speedup vs baseline: 1.0337x; 1.0337x over previous
//
#include <hip/hip_runtime.h>
#include <hip/hip_bf16.h>

// Problem constants (from reference)
#define BATCH_N   16384
#define FEAT      128      // MOVIE_FEAT == USER_FEAT
#define NNBR      50
#define NUM_MOVIES_N 100000

typedef short  short8  __attribute__((ext_vector_type(8)));
typedef float  floatx4 __attribute__((ext_vector_type(4)));
typedef unsigned int u32;

__device__ __forceinline__ __hip_bfloat16 f2bf(float x) { return __float2bfloat16(x); }
__device__ __forceinline__ float bfb2f(short s) {
  union { u32 u; float f; } c; c.u = ((u32)(unsigned short)s) << 16; return c.f;
}

__device__ __forceinline__ floatx4 mfma16(short8 a, short8 b, floatx4 c) {
  return __builtin_amdgcn_mfma_f32_16x16x32_bf16(a, b, c, 0, 0, 0);
}

// ---------------------------------------------------------------------------
// conv_table: fp32 movie_table -> bf16 copy (25 MB, L2/L3-resident for gathers)
// ---------------------------------------------------------------------------
__global__ __launch_bounds__(256) void conv_table(
    const float* __restrict__ t, __hip_bfloat16* __restrict__ tb) {
  size_t i = ((size_t)blockIdx.x * 256 + threadIdx.x) * 8;
  float4 v0 = *(const float4*)(t + i);
  float4 v1 = *(const float4*)(t + i + 4);
  __hip_bfloat16 o[8];
  o[0] = f2bf(v0.x); o[1] = f2bf(v0.y); o[2] = f2bf(v0.z); o[3] = f2bf(v0.w);
  o[4] = f2bf(v1.x); o[5] = f2bf(v1.y); o[6] = f2bf(v1.z); o[7] = f2bf(v1.w);
  *(short8*)(tb + i) = *(short8*)o;
}

// ---------------------------------------------------------------------------
// prep: bf16 transposed weights Wt[n][k] + fused bias bu+bm.
// WcatT=[Wu;Wm]^T [256n][256k]; W1T [256][256]; W2T [128n][256k]; WmT [256n][128k]
// ---------------------------------------------------------------------------
__global__ __launch_bounds__(256) void prep_kernel(
    const float* __restrict__ Wu, const float* __restrict__ Wm,
    const float* __restrict__ W1, const float* __restrict__ W2,
    const float* __restrict__ bu, const float* __restrict__ bm,
    __hip_bfloat16* __restrict__ WcatT, __hip_bfloat16* __restrict__ WmT,
    __hip_bfloat16* __restrict__ W1T,  __hip_bfloat16* __restrict__ W2T,
    float* __restrict__ bc) {
  int idx = blockIdx.x * 256 + threadIdx.x;   // 0..65535
  int n = idx & 255, k = idx >> 8;
  float v = (k < 128) ? Wu[k * 256 + n] : Wm[(k - 128) * 256 + n];
  WcatT[n * 256 + k] = f2bf(v);
  W1T[n * 256 + k]   = f2bf(W1[k * 256 + n]);
  if (k < 128) WmT[n * 128 + k] = f2bf(Wm[k * 256 + n]);
  if (idx < 32768) {
    int k2 = idx >> 7, n2 = idx & 127;
    W2T[n2 * 256 + k2] = f2bf(W2[k2 * 128 + n2]);
  }
  if (idx < 256) bc[idx] = bu[idx] + bm[idx];
}

// ---------------------------------------------------------------------------
// gather_user: one WAVE per batch row. Lane slice = 16 B; quad q handles
// nbr 4*it+q -> 13 wave-loads of 1 KB. Cross-quad shfl_xor reduce.
// ---------------------------------------------------------------------------
__global__ __launch_bounds__(256) void gather_user(
    const float* __restrict__ users, const int* __restrict__ nbr_ids,
    const __hip_bfloat16* __restrict__ tb, __hip_bfloat16* __restrict__ A_user) {
  int row  = (blockIdx.x << 2) + (threadIdx.x >> 6);
  int lane = threadIdx.x & 63;
  int quad = lane >> 4, sl = lane & 15;
  const int* nb = nbr_ids + row * NNBR;
  float acc[8] = {0.f, 0.f, 0.f, 0.f, 0.f, 0.f, 0.f, 0.f};
  #pragma unroll
  for (int it = 0; it < 13; ++it) {
    int j = it * 4 + quad;
    if (j < NNBR) {
      int id = nb[j];
      short8 v = *(const short8*)(tb + (size_t)id * FEAT + sl * 8);
      #pragma unroll
      for (int e = 0; e < 8; ++e) acc[e] += bfb2f(v[e]);
    }
  }
  __hip_bfloat16 o[8];
  #pragma unroll
  for (int e = 0; e < 8; ++e) {
    float v = acc[e];
    v += __shfl_xor(v, 16, 64);
    v += __shfl_xor(v, 32, 64);
    o[e] = f2bf(v * (1.f / NNBR));
  }
  if (quad == 0)
    *(short8*)(A_user + (size_t)row * 256 + 128 + sl * 8) = *(short8*)o;
  float2 uv = ((const float2*)(users + (size_t)row * FEAT))[lane];
  __hip_bfloat162 t0; t0.x = f2bf(uv.x); t0.y = f2bf(uv.y);
  ((__hip_bfloat162*)(A_user + (size_t)row * 256))[lane] = t0;
}

// ---------------------------------------------------------------------------
// gemm_bv: barrier-free GEMM, weights in VGPRs, A-frags direct from global.
//   C[M][NTOT] = act(A[M][K0] @ Wt^T + bias)
// Block = 4 waves; wave w owns cols [blockIdx.y*128 + w*32, +32).
// Per wave: B frags (2 j x KK kc) persist in VGPRs; A-frags register-
// double-buffered one iter ahead so ~310 cy/SIMD of MFMA hides the load
// latency. No LDS, no barriers.
//
// R6 lesson: with default launch bounds the compiler capped VGPRs at 76 and
// SANK the B/A loads back into the loop (full latency exposed, MfmaUtil 5%).
// __launch_bounds__(256, 2) raises the cap to ~256 VGPRs -> bfr/abuf stay
// register-resident and the iter-ahead prefetch is real. IT is sized so each
// grid is exactly ~2 blocks/CU co-resident (2 waves/SIMD).
// ---------------------------------------------------------------------------
template <int K0, bool GATHER, bool RELU, bool OUTF32, int NTOT, int IT>
__global__ __launch_bounds__(256, 2) void gemm_bv(
    const __hip_bfloat16* __restrict__ Asrc,
    const int* __restrict__ pos_ids, const int* __restrict__ neg_ids,
    const __hip_bfloat16* __restrict__ Wt, const float* __restrict__ bias,
    float* __restrict__ Cf, __hip_bfloat16* __restrict__ Cb) {
  constexpr int KK = K0 / 32;
  const int lane = threadIdx.x & 63, wid = threadIdx.x >> 6;
  const int quad = lane >> 4, lrow = lane & 15;
  const int c0 = blockIdx.y * 128 + wid * 32;
  const long mbase = (long)blockIdx.x * (16 * IT);

  // persistent B fragments for this wave's 32 columns (64 VGPRs @ K0=256)
  short8 bfr[2][KK];
  #pragma unroll
  for (int j = 0; j < 2; ++j)
    #pragma unroll
    for (int kc = 0; kc < KK; ++kc)
      bfr[j][kc] = *(const short8*)(Wt + (size_t)(c0 + j * 16 + lrow) * K0 +
                                    kc * 32 + quad * 8);
  const float bv0 = bias[c0 + lrow];
  const float bv1 = bias[c0 + 16 + lrow];

  short8 abuf[2][KK];
  auto loadA = [&](int it, short8* dst) {
    long m = mbase + it * 16 + lrow;
    const __hip_bfloat16* rp;
    if (GATHER) {
      int id = (m < BATCH_N) ? pos_ids[m] : neg_ids[m - BATCH_N];
      rp = Asrc + (size_t)id * K0;
    } else {
      rp = Asrc + (size_t)m * K0;
    }
    #pragma unroll
    for (int kc = 0; kc < KK; ++kc)
      dst[kc] = *(const short8*)(rp + kc * 32 + quad * 8);
  };

  loadA(0, abuf[0]);
  #pragma unroll
  for (int it = 0; it < IT; ++it) {
    if (it + 1 < IT) loadA(it + 1, abuf[(it + 1) & 1]);
    const short8* af = abuf[it & 1];
    floatx4 p0a = {}, p0b = {}, p1a = {}, p1b = {};
    #pragma unroll
    for (int kc = 0; kc < KK; kc += 2) {
      p0a = mfma16(af[kc],     bfr[0][kc],     p0a);
      p1a = mfma16(af[kc],     bfr[1][kc],     p1a);
      p0b = mfma16(af[kc + 1], bfr[0][kc + 1], p0b);
      p1b = mfma16(af[kc + 1], bfr[1][kc + 1], p1b);
    }
    floatx4 a0 = p0a + p0b, a1 = p1a + p1b;
    long m0 = mbase + it * 16;
    #pragma unroll
    for (int r = 0; r < 4; ++r) {
      long row = m0 + quad * 4 + r;
      float v0 = a0[r] + bv0, v1 = a1[r] + bv1;
      if (RELU) { v0 = fmaxf(v0, 0.f); v1 = fmaxf(v1, 0.f); }
      if (OUTF32) {
        Cf[row * NTOT + c0 + lrow]      = v0;
        Cf[row * NTOT + c0 + 16 + lrow] = v1;
      } else {
        Cb[row * NTOT + c0 + lrow]      = f2bf(v0);
        Cb[row * NTOT + c0 + 16 + lrow] = f2bf(v1);
      }
    }
  }
}

// ---------------------------------------------------------------------------
extern "C" void kernel_launch(void* const* d_in, const int* in_sizes, int n_in,
                              void* d_out, int out_size, void* d_ws, size_t ws_size,
                              hipStream_t stream) {
  const float* users   = (const float*)d_in[0];
  // d_in[1] pos_movies, d_in[2] neg_movies, d_in[3] user_ids: unused by ref
  const int*   pos_ids = (const int*)d_in[4];
  const int*   neg_ids = (const int*)d_in[5];
  const int*   nbr_ids = (const int*)d_in[6];
  const float* table   = (const float*)d_in[7];
  const float* Wu = (const float*)d_in[8];
  const float* bu = (const float*)d_in[9];
  const float* Wm = (const float*)d_in[10];
  const float* bm = (const float*)d_in[11];
  const float* W1 = (const float*)d_in[12];
  const float* b1 = (const float*)d_in[13];
  const float* W2 = (const float*)d_in[14];
  const float* b2 = (const float*)d_in[15];
  float* out = (float*)d_out;

  // workspace carve (all 256B aligned). Total ~83 MB.
  char* p = (char*)d_ws;
  auto carve = [&](size_t bytes) { char* r = p; p += (bytes + 255) & ~(size_t)255; return r; };
  __hip_bfloat16* tb     = (__hip_bfloat16*)carve((size_t)NUM_MOVIES_N * FEAT * 2);
  __hip_bfloat16* WcatT  = (__hip_bfloat16*)carve(256 * 256 * 2);
  __hip_bfloat16* WmT    = (__hip_bfloat16*)carve(256 * 128 * 2);
  __hip_bfloat16* W1T    = (__hip_bfloat16*)carve(256 * 256 * 2);
  __hip_bfloat16* W2T    = (__hip_bfloat16*)carve(128 * 256 * 2);
  float*          bc     = (float*)carve(256 * 4);
  __hip_bfloat16* A_user = (__hip_bfloat16*)carve((size_t)BATCH_N * 256 * 2);
  __hip_bfloat16* E      = (__hip_bfloat16*)carve((size_t)3 * BATCH_N * 256 * 2);
  __hip_bfloat16* H      = (__hip_bfloat16*)carve((size_t)3 * BATCH_N * 256 * 2);

  conv_table<<<NUM_MOVIES_N * FEAT / (256 * 8), 256, 0, stream>>>(table, tb);
  prep_kernel<<<256, 256, 0, stream>>>(Wu, Wm, W1, W2, bu, bm,
                                       WcatT, WmT, W1T, W2T, bc);
  gather_user<<<BATCH_N / 4, 256, 0, stream>>>(users, nbr_ids, tb, A_user);

  // E rows: [0,B) user | [B,2B) pos | [2B,3B) neg
  // L0-user: E[0:B] = A_user @ WcatT^T + bc   (M=16384,K=256,N=256) 512 blk
  gemm_bv<256, false, false, false, 256, 4>
      <<<dim3(BATCH_N / 64, 2), 256, 0, stream>>>(
          A_user, nullptr, nullptr, WcatT, bc, nullptr, E);
  // L0-pn: E[B:3B] = tb[ids] @ WmT^T + bm     (M=32768,K=128,N=256) 1024 blk
  gemm_bv<128, true, false, false, 256, 4>
      <<<dim3(2 * BATCH_N / 64, 2), 256, 0, stream>>>(
          tb, pos_ids, neg_ids, WmT, bm, nullptr, E + (size_t)BATCH_N * 256);
  // L1: H = relu(E @ W1T^T + b1)              (M=49152,K=256,N=256) 512 blk
  gemm_bv<256, false, true, false, 256, 12>
      <<<dim3(3 * BATCH_N / 192, 2), 256, 0, stream>>>(
          E, nullptr, nullptr, W1T, b1, nullptr, H);
  // L2: out = relu(H @ W2T^T + b2)            (M=49152,K=256,N=128) 512 blk
  gemm_bv<256, false, true, true, 128, 6>
      <<<dim3(3 * BATCH_N / 96, 1), 256, 0, stream>>>(
          H, nullptr, nullptr, W2T, b2, out, nullptr);
}